// Round 9
// baseline (537.131 us; speedup 1.0000x reference)
//
#include <hip/hip_runtime.h>
#include <hip/hip_bf16.h>
#include <hip/hip_cooperative_groups.h>
#include <math.h>

#define HW 4096
#define LN_EPS 1e-5f

namespace cg = cooperative_groups;

typedef _Float16 half4v __attribute__((ext_vector_type(4)));
typedef _Float16 half8v __attribute__((ext_vector_type(8)));
typedef float float4v __attribute__((ext_vector_type(4)));
typedef __fp16 fp16v2 __attribute__((ext_vector_type(2)));

#if __has_builtin(__builtin_amdgcn_exp2f)
#define EXP2F(x) __builtin_amdgcn_exp2f(x)
#else
#define EXP2F(x) exp2f(x)
#endif

__device__ __forceinline__ half4v lo4(half8v v) { return __builtin_shufflevector(v, v, 0, 1, 2, 3); }
__device__ __forceinline__ half4v hi4(half8v v) { return __builtin_shufflevector(v, v, 4, 5, 6, 7); }

__device__ __forceinline__ void gload_lds16(const _Float16* g, _Float16* l) {
#if __has_builtin(__builtin_amdgcn_global_load_lds)
    __builtin_amdgcn_global_load_lds(
        (const __attribute__((address_space(1))) void*)(const void*)g,
        (__attribute__((address_space(3))) void*)(void*)l, 16, 0, 0);
#else
    int lane = threadIdx.x & 63;
    *(half8v*)(l + lane * 8) = *(const half8v*)g;
#endif
}

struct P {
    const float *x, *wq, *wp, *b_proj, *pb, *gamma, *beta;
    _Float16 *xt, *qa, *ka, *va;
    float *op, *lp, *pos;
    _Float16 *wqh, *wph;
    float* out;
};

// ---------------- phase A: x transpose + weight convert + pos bilinear (896 units) -----
__device__ __forceinline__ void phaseA(int u, int t, char* smem, const P& pp) {
    int w = t >> 6, lane = t & 63;
    if (u < 512) { // transpose x [512][4096] f32 -> xt [4096][512] f16
        _Float16 (*tile)[65] = (_Float16(*)[65])smem;
        int c0 = (u >> 6) * 64, p0 = (u & 63) * 64;
        #pragma unroll
        for (int r = 0; r < 16; r++)
            tile[w * 16 + r][lane] = (_Float16)pp.x[(c0 + w * 16 + r) * HW + p0 + lane];
        __syncthreads();
        int cgx = (t & 15) * 4, pr = t >> 4;
        #pragma unroll
        for (int r = 0; r < 4; r++) {
            int p = pr + r * 16;
            half4v v;
            #pragma unroll
            for (int k = 0; k < 4; k++) v[k] = tile[cgx + k][p];
            *(half4v*)&pp.xt[(p0 + p) * 512 + c0 + cgx] = v;
        }
        return;
    }
    int i = (u - 512) * 256 + t;
    const float qs = 0.17677669529663687f * 1.4426950408889634f; // scale * log2(e)
    if (i < 49152) { // wq, Q rows pre-scaled
        float s = (i < 16384) ? qs : 1.0f;
        float4v a = *(const float4v*)(pp.wq + i * 8);
        float4v b = *(const float4v*)(pp.wq + i * 8 + 4);
        half8v h;
        #pragma unroll
        for (int k = 0; k < 4; k++) { h[k] = (_Float16)(a[k] * s); h[4 + k] = (_Float16)(b[k] * s); }
        *(half8v*)(pp.wqh + i * 8) = h;
    } else if (i < 65536) { // wp
        int j = i - 49152;
        float4v a = *(const float4v*)(pp.wp + j * 8);
        float4v b = *(const float4v*)(pp.wp + j * 8 + 4);
        half8v h;
        #pragma unroll
        for (int k = 0; k < 4; k++) { h[k] = (_Float16)a[k]; h[4 + k] = (_Float16)b[k]; }
        *(half8v*)(pp.wph + j * 8) = h;
    } else { // pos bilinear 16->64, times log2(e)
        int j = i - 65536;
        int h = j >> 12, p = j & 4095, y = p >> 6, xx = p & 63;
        float sy = y * 0.25f - 0.375f, sx = xx * 0.25f - 0.375f;
        float fy = floorf(sy), fx = floorf(sx);
        float wy = sy - fy, wx = sx - fx;
        int y0 = (int)fy, x0 = (int)fx;
        int y1 = y0 + 1 < 15 ? y0 + 1 : 15;
        int x1 = x0 + 1 < 15 ? x0 + 1 : 15;
        y0 = y0 > 0 ? y0 : 0;
        x0 = x0 > 0 ? x0 : 0;
        const float* src = pp.pb + h * 256;
        float v = (1.f - wy) * ((1.f - wx) * src[y0 * 16 + x0] + wx * src[y0 * 16 + x1]) +
                  wy * ((1.f - wx) * src[y1 * 16 + x0] + wx * src[y1 * 16 + x1]);
        pp.pos[j] = v * 1.4426950408889634f;
    }
}

// ---------------- phase B: QKV GEMM, 768 units of 64n x 64p ----------------------------
// qa [h][q][d]; ka: [h][j>>4][lane=(d>>3)*16+(j&15)][idx=d&7]
// va: [h][j>>4][lane=((j>>2)&3)*16+(d&15)][idx=(d>>4)*4+(j&3)]
__device__ __forceinline__ void phaseB(int u, int t, const P& pp) {
    int w = t >> 6, lane = t & 63, quad = lane >> 4, l16 = lane & 15;
    int n0 = (u >> 6) * 64;
    int p0 = (u & 63) * 64;
    const _Float16* aptr = pp.xt + (p0 + w * 16 + l16) * 512 + quad * 8;
    const _Float16* bptr = pp.wqh + (n0 + l16) * 512 + quad * 8;
    float4v acc[4] = {};
    #pragma unroll 4
    for (int kc = 0; kc < 16; kc++) {
        half8v a = *(const half8v*)(aptr + kc * 32);
        #pragma unroll
        for (int nt = 0; nt < 4; nt++) {
            half8v b = *(const half8v*)(bptr + nt * 16 * 512 + kc * 32);
            acc[nt] = __builtin_amdgcn_mfma_f32_16x16x32_f16(a, b, acc[nt], 0, 0, 0);
        }
    }
    #pragma unroll
    for (int nt = 0; nt < 4; nt++) {
        int o = n0 + nt * 16 + l16;
        #pragma unroll
        for (int r = 0; r < 4; r++) {
            int p = p0 + w * 16 + quad * 4 + r;
            _Float16 v = (_Float16)acc[nt][r];
            if (o < 256) {
                pp.qa[(o >> 5) * 131072 + p * 32 + (o & 31)] = v;
            } else if (o < 512) {
                int oc = o - 256, hh = oc >> 5, d = oc & 31;
                pp.ka[hh * 131072 + (p >> 4) * 512 + ((d >> 3) * 16 + (p & 15)) * 8 + (d & 7)] = v;
            } else {
                int oc = o - 512, hh = oc >> 5, d = oc & 31;
                pp.va[hh * 131072 + (p >> 4) * 512 + (((p >> 2) & 3) * 16 + (d & 15)) * 8 +
                      (d >> 4) * 4 + (p & 3)] = v;
            }
        }
    }
}

// ---------------- phase C: attention, 1024 units (8h x 4jq x 32qb) ---------------------
__device__ __forceinline__ void phaseC(int u, int t, char* smem, const P& pp) {
    _Float16* kbuf = (_Float16*)smem;            // 2 x 2048
    _Float16* vbuf = (_Float16*)(smem + 8192);   // 2 x 2048
    float* posl = (float*)(smem + 16384);        // 1024
    int w = t >> 6, lane = t & 63, quad = lane >> 4, l16 = lane & 15;
    int h = u & 7;
    int jq = (u >> 3) & 3;
    int qb = u >> 5;
    int q0 = qb * 128 + w * 32;
    float* opp = pp.op + jq * 1048576;
    float* lpp = pp.lp + jq * 32768;

    *(float4v*)(posl + t * 4) = *(const float4v*)(pp.pos + h * HW + jq * 1024 + t * 4);

    half8v qf0 = *(const half8v*)(pp.qa + h * 131072 + (q0 + l16) * 32 + quad * 8);
    half8v qf1 = *(const half8v*)(pp.qa + h * 131072 + (q0 + 16 + l16) * 32 + quad * 8);

    const _Float16* kg = pp.ka + h * 131072 + jq * 32768;
    const _Float16* vg = pp.va + h * 131072 + jq * 32768;

    gload_lds16(kg + (w * 64 + lane) * 8, kbuf + w * 512);
    gload_lds16(vg + (w * 64 + lane) * 8, vbuf + w * 512);

    float4v o00 = {}, o01 = {}, o10 = {}, o11 = {};
    float lsum0 = 0.f, lsum1 = 0.f;
    const fp16v2 one2 = {(__fp16)1.0f, (__fp16)1.0f};

    for (int tile = 0; tile < 16; tile++) {
        int buf = tile & 1;
        __syncthreads();
        if (tile + 1 < 16) {
            gload_lds16(kg + (tile + 1) * 2048 + (w * 64 + lane) * 8,
                        kbuf + (buf ^ 1) * 2048 + w * 512);
            gload_lds16(vg + (tile + 1) * 2048 + (w * 64 + lane) * 8,
                        vbuf + (buf ^ 1) * 2048 + w * 512);
        }
        #pragma unroll
        for (int w16 = 0; w16 < 4; w16++) {
            half8v kf = *(const half8v*)(kbuf + buf * 2048 + w16 * 512 + lane * 8);
            half8v vf = *(const half8v*)(vbuf + buf * 2048 + w16 * 512 + lane * 8);
            float4v pbv = *(const float4v*)(posl + tile * 64 + w16 * 16 + quad * 4);

            float4v s0 = __builtin_amdgcn_mfma_f32_16x16x32_f16(kf, qf0, pbv, 0, 0, 0);
            float4v s1 = __builtin_amdgcn_mfma_f32_16x16x32_f16(kf, qf1, pbv, 0, 0, 0);

            float e0 = EXP2F(s0[0]);
            float e1 = EXP2F(s0[1]);
            float e2 = EXP2F(s0[2]);
            float e3 = EXP2F(s0[3]);
            float f0 = EXP2F(s1[0]);
            float f1 = EXP2F(s1[1]);
            float f2 = EXP2F(s1[2]);
            float f3 = EXP2F(s1[3]);

            fp16v2 a01 = __builtin_amdgcn_cvt_pkrtz(e0, e1);
            fp16v2 a23 = __builtin_amdgcn_cvt_pkrtz(e2, e3);
            fp16v2 b01 = __builtin_amdgcn_cvt_pkrtz(f0, f1);
            fp16v2 b23 = __builtin_amdgcn_cvt_pkrtz(f2, f3);
            half4v pa0 = __builtin_bit_cast(half4v, __builtin_shufflevector(a01, a23, 0, 1, 2, 3));
            half4v pa1 = __builtin_bit_cast(half4v, __builtin_shufflevector(b01, b23, 0, 1, 2, 3));

#if __has_builtin(__builtin_amdgcn_fdot2)
            lsum0 = __builtin_amdgcn_fdot2(a01, one2, lsum0, false);
            lsum0 = __builtin_amdgcn_fdot2(a23, one2, lsum0, false);
            lsum1 = __builtin_amdgcn_fdot2(b01, one2, lsum1, false);
            lsum1 = __builtin_amdgcn_fdot2(b23, one2, lsum1, false);
#else
            lsum0 += (e0 + e1) + (e2 + e3);
            lsum1 += (f0 + f1) + (f2 + f3);
#endif
            o00 = __builtin_amdgcn_mfma_f32_16x16x16f16(pa0, lo4(vf), o00, 0, 0, 0);
            o01 = __builtin_amdgcn_mfma_f32_16x16x16f16(pa0, hi4(vf), o01, 0, 0, 0);
            o10 = __builtin_amdgcn_mfma_f32_16x16x16f16(pa1, lo4(vf), o10, 0, 0, 0);
            o11 = __builtin_amdgcn_mfma_f32_16x16x16f16(pa1, hi4(vf), o11, 0, 0, 0);
        }
    }
    lsum0 += __shfl_xor(lsum0, 16, 64);
    lsum0 += __shfl_xor(lsum0, 32, 64);
    lsum1 += __shfl_xor(lsum1, 16, 64);
    lsum1 += __shfl_xor(lsum1, 32, 64);
    #pragma unroll
    for (int r = 0; r < 4; r++) {
        int qr = quad * 4 + r;
        int qi0 = q0 + qr, qi1 = q0 + 16 + qr;
        opp[qi0 * 256 + h * 32 + l16] = o00[r];
        opp[qi0 * 256 + h * 32 + 16 + l16] = o01[r];
        opp[qi1 * 256 + h * 32 + l16] = o10[r];
        opp[qi1 * 256 + h * 32 + 16 + l16] = o11[r];
    }
    if (quad == 0) {
        lpp[(q0 + l16) * 8 + h] = lsum0;
        lpp[(q0 + 16 + l16) * 8 + h] = lsum1;
    }
}

// ---------------- phase D: combine + proj GEMM + residual + LayerNorm (256 units) ------
__device__ __forceinline__ void phaseD(int u, int t, char* smem, const P& pp) {
    _Float16* ys = (_Float16*)smem;                        // 16 x 264
    float (*red)[4][16] = (float(*)[4][16])(smem + 8448);  // [2][4][16]
    int w = t >> 6, lane = t & 63, quad = lane >> 4, l16 = lane & 15;
    int p0 = u * 16;
    #pragma unroll
    for (int g4 = 0; g4 < 4; g4++) {
        int g = t + g4 * 256;
        int p = g >> 6, cgx = (g & 63) * 4;
        int pi = p0 + p;
        float4v a0 = *(const float4v*)(pp.op + pi * 256 + cgx);
        float4v a1 = *(const float4v*)(pp.op + 1048576 + pi * 256 + cgx);
        float4v a2 = *(const float4v*)(pp.op + 2097152 + pi * 256 + cgx);
        float4v a3 = *(const float4v*)(pp.op + 3145728 + pi * 256 + cgx);
        int hh = cgx >> 5;
        float l = pp.lp[pi * 8 + hh] + pp.lp[32768 + pi * 8 + hh] +
                  pp.lp[65536 + pi * 8 + hh] + pp.lp[98304 + pi * 8 + hh];
        float inv = 1.f / l;
        half4v yv;
        #pragma unroll
        for (int k = 0; k < 4; k++) yv[k] = (_Float16)(((a0[k] + a1[k]) + (a2[k] + a3[k])) * inv);
        *(half4v*)(ys + p * 264 + cgx) = yv;
    }
    __syncthreads();
    float4v acc[8] = {};
    #pragma unroll
    for (int kc = 0; kc < 8; kc++) {
        half8v b = *(const half8v*)(ys + l16 * 264 + kc * 32 + quad * 8);
        #pragma unroll
        for (int mt = 0; mt < 8; mt++) {
            half8v a = *(const half8v*)(pp.wph + (w * 128 + mt * 16 + l16) * 256 + kc * 32 + quad * 8);
            acc[mt] = __builtin_amdgcn_mfma_f32_16x16x32_f16(a, b, acc[mt], 0, 0, 0);
        }
    }
    int p = p0 + l16;
    float sum = 0.f, sumsq = 0.f;
    #pragma unroll
    for (int mt = 0; mt < 8; mt++)
        #pragma unroll
        for (int r = 0; r < 4; r++) {
            int c = w * 128 + mt * 16 + quad * 4 + r;
            float v = acc[mt][r] + pp.b_proj[c] + pp.x[c * HW + p];
            acc[mt][r] = v;
            sum += v;
            sumsq += v * v;
        }
    sum += __shfl_xor(sum, 16, 64);
    sum += __shfl_xor(sum, 32, 64);
    sumsq += __shfl_xor(sumsq, 16, 64);
    sumsq += __shfl_xor(sumsq, 32, 64);
    if (quad == 0) { red[0][w][l16] = sum; red[1][w][l16] = sumsq; }
    __syncthreads();
    float s0 = (red[0][0][l16] + red[0][1][l16]) + (red[0][2][l16] + red[0][3][l16]);
    float s1 = (red[1][0][l16] + red[1][1][l16]) + (red[1][2][l16] + red[1][3][l16]);
    float mean = s0 * (1.f / 512.f);
    float var = s1 * (1.f / 512.f) - mean * mean;
    float rstd = rsqrtf(var + LN_EPS);
    #pragma unroll
    for (int mt = 0; mt < 8; mt++)
        #pragma unroll
        for (int r = 0; r < 4; r++) {
            int c = w * 128 + mt * 16 + quad * 4 + r;
            pp.out[c * HW + p] = (acc[mt][r] - mean) * rstd * pp.gamma[c] + pp.beta[c];
        }
}

// ---------------- cooperative mega-kernel (persistent blocks) --------------------------
__global__ __launch_bounds__(256, 4) void k_coop(P pp) {
    __shared__ __attribute__((aligned(16))) char smem[24576];
    cg::grid_group grid = cg::this_grid();
    int G = gridDim.x, bid = blockIdx.x, t = threadIdx.x;
    for (int u = bid; u < 896; u += G) { __syncthreads(); phaseA(u, t, smem, pp); }
    __threadfence();
    grid.sync();
    for (int u = bid; u < 768; u += G) phaseB(u, t, pp);
    __threadfence();
    grid.sync();
    for (int u = bid; u < 1024; u += G) { __syncthreads(); phaseC(u, t, smem, pp); }
    __threadfence();
    grid.sync();
    for (int u = bid; u < 256; u += G) { __syncthreads(); phaseD(u, t, smem, pp); }
}

// ---------------- fallback wrappers (separate launches, R7-equivalent) -----------------
__global__ __launch_bounds__(256) void kA(P pp) {
    __shared__ __attribute__((aligned(16))) char smem[8320];
    phaseA(blockIdx.x, threadIdx.x, smem, pp);
}
__global__ __launch_bounds__(256) void kB(P pp) { phaseB(blockIdx.x, threadIdx.x, pp); }
__global__ __launch_bounds__(256, 4) void kC(P pp) {
    __shared__ __attribute__((aligned(16))) char smem[24576];
    phaseC(blockIdx.x, threadIdx.x, smem, pp);
}
__global__ __launch_bounds__(256) void kD(P pp) {
    __shared__ __attribute__((aligned(16))) char smem[9216];
    phaseD(blockIdx.x, threadIdx.x, smem, pp);
}

extern "C" void kernel_launch(void* const* d_in, const int* in_sizes, int n_in,
                              void* d_out, int out_size, void* d_ws, size_t ws_size,
                              hipStream_t stream) {
    char* ws = (char*)d_ws;
    P pp;
    pp.x      = (const float*)d_in[0];
    pp.wq     = (const float*)d_in[1];
    pp.wp     = (const float*)d_in[2];
    pp.b_proj = (const float*)d_in[3];
    pp.pb     = (const float*)d_in[4];
    pp.gamma  = (const float*)d_in[5];
    pp.beta   = (const float*)d_in[6];
    pp.xt  = (_Float16*)(ws);              // 4194304
    pp.qa  = (_Float16*)(ws + 4194304);    // 2097152
    pp.ka  = (_Float16*)(ws + 6291456);    // 2097152
    pp.va  = (_Float16*)(ws + 8388608);    // 2097152
    pp.op  = (float*)   (ws + 10485760);   // 16777216
    pp.lp  = (float*)   (ws + 27262976);   // 524288
    pp.pos = (float*)   (ws + 27787264);   // 131072
    pp.wqh = (_Float16*)(ws + 27918336);   // 786432
    pp.wph = (_Float16*)(ws + 28704768);   // 262144
    pp.out = (float*)d_out;

    int occ = 0;
    hipError_t e = hipOccupancyMaxActiveBlocksPerMultiprocessor(&occ, (const void*)k_coop, 256, 0);
    bool done = false;
    if (e == hipSuccess && occ > 0) {
        int grid = occ * 256;
        if (grid > 1024) grid = 1024;
        void* args[] = {&pp};
        if (hipLaunchCooperativeKernel((void*)k_coop, dim3(grid), dim3(256), args, 0, stream)
            == hipSuccess)
            done = true;
    }
    if (!done) {
        kA<<<896, 256, 0, stream>>>(pp);
        kB<<<768, 256, 0, stream>>>(pp);
        kC<<<1024, 256, 0, stream>>>(pp);
        kD<<<256, 256, 0, stream>>>(pp);
    }
}